// Round 5
// baseline (27824.536 us; speedup 1.0000x reference)
//
#include <hip/hip_runtime.h>
#include <math.h>

namespace {

constexpr int Bb = 1024;
constexpr int Tn = 64;
constexpr int Dn = 8;
constexpr int Hn = 64;
constexpr int Wn = 128;
constexpr int BT = 4;     // batch rows per block
constexpr int NT = 1024;  // threads per block (16 waves)

// Tsit5 tableau
constexpr float A21 = 0.161f;
constexpr float A31 = -0.008480655492356989f, A32 = 0.335480655492357f;
constexpr float A41 = 2.8971530571054935f, A42 = -6.359448489975075f, A43 = 4.3622954328695815f;
constexpr float A51 = 5.325864828439257f, A52 = -11.748883564062828f, A53 = 7.4955393428898365f, A54 = -0.09249506636175525f;
constexpr float A61 = 5.86145544294642f, A62 = -12.92096931784711f, A63 = 8.159367898576159f, A64 = -0.071584973281401f, A65 = -0.028269050394068383f;
constexpr float Bc1 = 0.09646076681806523f, Bc2 = 0.01f, Bc3 = 0.4798896504144996f;
constexpr float Bc4 = 1.379008574103742f, Bc5 = -3.290069515436081f, Bc6 = 2.324710524099774f;

typedef float f4v __attribute__((ext_vector_type(4)));

__device__ inline float softplus_f(float x) {
  return fmaxf(x, 0.f) + log1pf(expf(-fabsf(x)));
}
__device__ inline float dot4v(f4v w, f4v a) {
  return w.x * a.x + w.y * a.y + w.z * a.z + w.w * a.w;
}

} // namespace

// Persistent per-batch-tile NeuralCDE integrator, v5.
// 1024 threads (16 waves), 4 batch rows, 256 blocks = 1/CU.
// Two changes vs v4 (both attack the 40 GB scratch-spill that R1-R4 showed):
//  (1) LDS padded past 80 KB -> only ONE 1024-thr WG fits per CU -> the
//      backend's max waves/EU is 4 by arithmetic -> RA budget = 128 VGPRs.
//      (Attributes amdgpu_waves_per_eu / amdgpu_num_vgpr were ignored in
//      R2/R4; LDS-limited occupancy cannot be.)
//  (2) Weights are named ext_vector SSA values, not allocas -> cannot be
//      demoted to scratch by a failed SROA; only RA can spill them, and
//      demand (~120) <= budget (128).
__attribute__((amdgpu_waves_per_eu(4, 4)))
__global__ __launch_bounds__(NT)
void ncde_kernel(const float* __restrict__ xs,
                 const float* __restrict__ iw1, const float* __restrict__ ib1,
                 const float* __restrict__ iw2, const float* __restrict__ ib2,
                 const float* __restrict__ iw3, const float* __restrict__ ib3,
                 const float* __restrict__ vw1, const float* __restrict__ vb1,
                 const float* __restrict__ vw2, const float* __restrict__ vb2,
                 const float* __restrict__ vw3, const float* __restrict__ vb3,
                 const float* __restrict__ lw,  const float* __restrict__ lb,
                 float* __restrict__ out)
{
  __shared__ float xs_l[BT][Tn * Dn];     // 8 KB control path
  __shared__ float y_l[BT][Hn];
  __shared__ float ys_l[BT][Hn];
  __shared__ float K_l[6][BT][Hn];
  __shared__ float h1_l[BT][Wn];
  __shared__ float h2_l[BT][Wn];
  __shared__ float part_l[8][BT][Wn];     // 16 KB k-split partials
  __shared__ float dxs_l[BT][Dn];
  __shared__ float lw_l[Hn];
  __shared__ float lds_force_1wg[12288];  // 48 KB pad -> total ~85.5 KB > 80 KB

  const int tid = threadIdx.x;
  const int oo  = tid & 127;              // output index for L1/L2
  const int g   = tid >> 7;               // k-split group 0..7
  const int b0  = blockIdx.x * BT;

  // ---- weights -> named SSA vector values (88 f32/thread) ----
  const f4v* p3 = (const f4v*)(vw3 + (tid >> 1) * Wn + (tid & 1) * 64);
  const f4v w3_0 = p3[0],  w3_1 = p3[1],  w3_2 = p3[2],  w3_3 = p3[3];
  const f4v w3_4 = p3[4],  w3_5 = p3[5],  w3_6 = p3[6],  w3_7 = p3[7];
  const f4v w3_8 = p3[8],  w3_9 = p3[9],  w3_10 = p3[10], w3_11 = p3[11];
  const f4v w3_12 = p3[12], w3_13 = p3[13], w3_14 = p3[14], w3_15 = p3[15];
  const f4v* p2 = (const f4v*)(vw2 + oo * Wn + g * 16);
  const f4v w2_0 = p2[0], w2_1 = p2[1], w2_2 = p2[2], w2_3 = p2[3];
  const f4v* p1 = (const f4v*)(vw1 + oo * Hn + g * 8);
  const f4v w1_0 = p1[0], w1_1 = p1[1];
  const float b3r = vb3[tid >> 1];
  const float b2r = vb2[oo];
  const float b1r = vb1[oo];
  const float lb0 = lb[0];

  // opaque guard: keeps the LDS pad alive (lb0 is runtime data; the
  // compiler cannot prove this branch dead, so the array must exist)
  if (lb0 == 1.2345678e30f) {
    lds_force_1wg[tid] = lb0;
    out[0] = lds_force_1wg[tid ^ 1];
  }

  // ---- stage this block's xs rows ----
  if (tid < 512)
    ((float4*)&xs_l[0][0])[tid] = ((const float4*)(xs + b0 * Tn * Dn))[tid];
  if (tid < Hn) lw_l[tid] = lw[tid];
  __syncthreads();

  // ---- initial MLP (relu, relu, identity) ----
  if (tid < 512) {
    const int b = tid >> 7;
    float acc = ib1[oo];
    #pragma unroll
    for (int k = 0; k < Dn; ++k) acc += iw1[oo * Dn + k] * xs_l[b][k];
    h1_l[b][oo] = fmaxf(acc, 0.f);
  }
  __syncthreads();
  if (tid < 512) {
    const int b = tid >> 7;
    float acc = ib2[oo];
    const f4v* wrow = (const f4v*)(iw2 + oo * Wn);
    #pragma unroll
    for (int k4 = 0; k4 < Wn / 4; ++k4)
      acc += dot4v(wrow[k4], *(const f4v*)&h1_l[b][k4 * 4]);
    h2_l[b][oo] = fmaxf(acc, 0.f);
  }
  __syncthreads();
  if (tid < BT * Hn) {
    const int b = tid >> 6, h = tid & (Hn - 1);
    float acc = ib3[h];
    const f4v* wrow = (const f4v*)(iw3 + h * Wn);
    #pragma unroll
    for (int k4 = 0; k4 < Wn / 4; ++k4)
      acc += dot4v(wrow[k4], *(const f4v*)&h2_l[b][k4 * 4]);
    y_l[b][h] = acc;
  }
  __syncthreads();

  auto readout = [&](int t) {
    if (tid < BT * Hn) {
      const int wv = tid >> 6, h = tid & (Hn - 1);
      float p = lw_l[h] * y_l[wv][h];
      #pragma unroll
      for (int off = 32; off > 0; off >>= 1) p += __shfl_xor(p, off, 64);
      if (h == 0) out[(b0 + wv) * Tn + t] = 1.f / (1.f + expf(-(p + lb0)));
    }
  };
  readout(0);

  // accumulate weight-vector w against activation rows [0..3] of arr
  #define ACC4(wv, arr, base, c) {                                   \
    a0 += dot4v(wv, *(const f4v*)&arr[0][(base) + (c) * 4]);         \
    a1 += dot4v(wv, *(const f4v*)&arr[1][(base) + (c) * 4]);         \
    a2 += dot4v(wv, *(const f4v*)&arr[2][(base) + (c) * 4]);         \
    a3 += dot4v(wv, *(const f4v*)&arr[3][(base) + (c) * 4]); }

  // ---- 63 Tsit5 steps ----
  for (int t = 0; t < Tn - 1; ++t) {
    if (tid < BT * Hn) {
      const int b = tid >> 6, h = tid & (Hn - 1);
      ys_l[b][h] = y_l[b][h];
    } else if (tid < BT * Hn + BT * Dn) {
      const int r = tid - BT * Hn;
      const int b = r >> 3, d = r & 7;
      dxs_l[b][d] = xs_l[b][(t + 1) * Dn + d] - xs_l[b][t * Dn + d];  // dt*dX/dt
    }
    __syncthreads();

    #pragma unroll
    for (int s = 0; s < 6; ++s) {
      // ---- vf L1: [4,64]->[4,128], k-split 8 ways ----
      {
        float a0 = 0, a1 = 0, a2 = 0, a3 = 0;
        const int base = g * 8;
        ACC4(w1_0, ys_l, base, 0)
        ACC4(w1_1, ys_l, base, 1)
        part_l[g][0][oo] = a0; part_l[g][1][oo] = a1;
        part_l[g][2][oo] = a2; part_l[g][3][oo] = a3;
      }
      __syncthreads();
      if (tid < 512) {
        const int b = tid >> 7;
        float acc = b1r;
        #pragma unroll
        for (int j = 0; j < 8; ++j) acc += part_l[j][b][oo];
        h1_l[b][oo] = softplus_f(acc);
      }
      __syncthreads();
      // ---- vf L2: [4,128]->[4,128], k-split 8 ways ----
      {
        float a0 = 0, a1 = 0, a2 = 0, a3 = 0;
        const int base = g * 16;
        ACC4(w2_0, h1_l, base, 0)
        ACC4(w2_1, h1_l, base, 1)
        ACC4(w2_2, h1_l, base, 2)
        ACC4(w2_3, h1_l, base, 3)
        part_l[g][0][oo] = a0; part_l[g][1][oo] = a1;
        part_l[g][2][oo] = a2; part_l[g][3][oo] = a3;
      }
      __syncthreads();
      if (tid < 512) {
        const int b = tid >> 7;
        float acc = b2r;
        #pragma unroll
        for (int j = 0; j < 8; ++j) acc += part_l[j][b][oo];
        h2_l[b][oo] = softplus_f(acc);
      }
      __syncthreads();
      // ---- vf L3: [4,128]->[4,512] (half-row/thread), tanh, einsum dx ----
      {
        float a0 = 0, a1 = 0, a2 = 0, a3 = 0;
        const int kh = (tid & 1) * 64;
        ACC4(w3_0,  h2_l, kh, 0)  ACC4(w3_1,  h2_l, kh, 1)
        ACC4(w3_2,  h2_l, kh, 2)  ACC4(w3_3,  h2_l, kh, 3)
        ACC4(w3_4,  h2_l, kh, 4)  ACC4(w3_5,  h2_l, kh, 5)
        ACC4(w3_6,  h2_l, kh, 6)  ACC4(w3_7,  h2_l, kh, 7)
        ACC4(w3_8,  h2_l, kh, 8)  ACC4(w3_9,  h2_l, kh, 9)
        ACC4(w3_10, h2_l, kh, 10) ACC4(w3_11, h2_l, kh, 11)
        ACC4(w3_12, h2_l, kh, 12) ACC4(w3_13, h2_l, kh, 13)
        ACC4(w3_14, h2_l, kh, 14) ACC4(w3_15, h2_l, kh, 15)
        const int d = (tid >> 1) & 7;     // row r3 = tid>>1 = h*8+d
        const int h = tid >> 4;
        #define L3RED(ab, b) {                                        \
          float p = ab;                                               \
          p += __shfl_xor(p, 1, 64);      /* join k-halves */         \
          p = tanhf(p + b3r) * dxs_l[b][d];                           \
          p += __shfl_xor(p, 2, 64);      /* reduce over d */         \
          p += __shfl_xor(p, 4, 64);                                  \
          p += __shfl_xor(p, 8, 64);                                  \
          if ((tid & 15) == 0) K_l[s][b][h] = p; }
        L3RED(a0, 0) L3RED(a1, 1) L3RED(a2, 2) L3RED(a3, 3)
        #undef L3RED
      }
      __syncthreads();
      // ---- stage prep / final update ----
      if (tid < BT * Hn) {
        const int b = tid >> 6, h = tid & (Hn - 1);
        float v = y_l[b][h];
        if (s == 0)      v += A21 * K_l[0][b][h];
        else if (s == 1) v += A31 * K_l[0][b][h] + A32 * K_l[1][b][h];
        else if (s == 2) v += A41 * K_l[0][b][h] + A42 * K_l[1][b][h] + A43 * K_l[2][b][h];
        else if (s == 3) v += A51 * K_l[0][b][h] + A52 * K_l[1][b][h] + A53 * K_l[2][b][h] + A54 * K_l[3][b][h];
        else if (s == 4) v += A61 * K_l[0][b][h] + A62 * K_l[1][b][h] + A63 * K_l[2][b][h] + A64 * K_l[3][b][h] + A65 * K_l[4][b][h];
        else             v += Bc1 * K_l[0][b][h] + Bc2 * K_l[1][b][h] + Bc3 * K_l[2][b][h]
                            + Bc4 * K_l[3][b][h] + Bc5 * K_l[4][b][h] + Bc6 * K_l[5][b][h];
        if (s < 5) ys_l[b][h] = v; else y_l[b][h] = v;
      }
      __syncthreads();
    }
    readout(t + 1);
  }
  #undef ACC4
}

extern "C" void kernel_launch(void* const* d_in, const int* in_sizes, int n_in,
                              void* d_out, int out_size, void* d_ws, size_t ws_size,
                              hipStream_t stream) {
  const float* xs  = (const float*)d_in[1];
  const float* iw1 = (const float*)d_in[2];
  const float* ib1 = (const float*)d_in[3];
  const float* iw2 = (const float*)d_in[4];
  const float* ib2 = (const float*)d_in[5];
  const float* iw3 = (const float*)d_in[6];
  const float* ib3 = (const float*)d_in[7];
  const float* vw1 = (const float*)d_in[8];
  const float* vb1 = (const float*)d_in[9];
  const float* vw2 = (const float*)d_in[10];
  const float* vb2 = (const float*)d_in[11];
  const float* vw3 = (const float*)d_in[12];
  const float* vb3 = (const float*)d_in[13];
  const float* lw  = (const float*)d_in[14];
  const float* lb  = (const float*)d_in[15];
  float* out = (float*)d_out;

  ncde_kernel<<<Bb / BT, NT, 0, stream>>>(xs, iw1, ib1, iw2, ib2, iw3, ib3,
                                          vw1, vb1, vw2, vb2, vw3, vb3, lw, lb, out);
}

// Round 7
// 25526.471 us; speedup vs baseline: 1.0900x; 1.0900x over previous
//
#include <hip/hip_runtime.h>
#include <math.h>

namespace {

constexpr int Bb = 1024;
constexpr int Tn = 64;
constexpr int Dn = 8;
constexpr int Hn = 64;
constexpr int Wn = 128;
constexpr int BT = 4;    // batch rows per block
constexpr int NT = 512;  // threads per block (8 waves) -> honored 128-VGPR budget

// Tsit5 tableau
constexpr float A21 = 0.161f;
constexpr float A31 = -0.008480655492356989f, A32 = 0.335480655492357f;
constexpr float A41 = 2.8971530571054935f, A42 = -6.359448489975075f, A43 = 4.3622954328695815f;
constexpr float A51 = 5.325864828439257f, A52 = -11.748883564062828f, A53 = 7.4955393428898365f, A54 = -0.09249506636175525f;
constexpr float A61 = 5.86145544294642f, A62 = -12.92096931784711f, A63 = 8.159367898576159f, A64 = -0.071584973281401f, A65 = -0.028269050394068383f;
constexpr float Bc1 = 0.09646076681806523f, Bc2 = 0.01f, Bc3 = 0.4798896504144996f;
constexpr float Bc4 = 1.379008574103742f, Bc5 = -3.290069515436081f, Bc6 = 2.324710524099774f;

typedef float f4v __attribute__((ext_vector_type(4)));

__device__ inline float softplus_f(float x) {
  return fmaxf(x, 0.f) + log1pf(expf(-fabsf(x)));
}
__device__ inline float dot4v(f4v w, f4v a) {
  return w.x * a.x + w.y * a.y + w.z * a.z + w.w * a.w;
}

} // namespace

// v7: all-f32 (R6 proved fp16 weights fail: ~1e3 error amplification over
// the 63-step integration). Weight residency split to fit the HONORED
// budgets (R1-R5: 512thr->128 VGPR, immovable):
//   regs: vw3 k in [0,64) (64 f32) + vw2 quarter-row (32) + vw1 quarter-row
//         (16) = 112 weight VGPRs + ~13 working <= 128 -> no spill.
//   LDS : vw3 k in [64,128) as float4 [k4][row] (128 KB) -> lane-consecutive
//         ds_read_b128, conflict-free; + activations ~22 KB = ~150 KB,
//         1 WG/CU (8 waves).
__global__ __launch_bounds__(NT)
void ncde_kernel(const float* __restrict__ xs,
                 const float* __restrict__ iw1, const float* __restrict__ ib1,
                 const float* __restrict__ iw2, const float* __restrict__ ib2,
                 const float* __restrict__ iw3, const float* __restrict__ ib3,
                 const float* __restrict__ vw1, const float* __restrict__ vb1,
                 const float* __restrict__ vw2, const float* __restrict__ vb2,
                 const float* __restrict__ vw3, const float* __restrict__ vb3,
                 const float* __restrict__ lw,  const float* __restrict__ lb,
                 float* __restrict__ out)
{
  __shared__ f4v   w3L[16][512];          // 128 KB: vw3 k in [64,128), [k4][row]
  __shared__ float part_l[4][BT][Wn];     // 8 KB k-split partials
  __shared__ float h1_l[BT][Wn];          // 2 KB
  __shared__ float h2_l[BT][Wn];          // 2 KB
  __shared__ float y_l[BT][Hn];
  __shared__ float ys_l[BT][Hn];
  __shared__ float K_l[6][BT][Hn];        // 6 KB
  __shared__ float dxs_l[BT][Dn];
  __shared__ float lw_l[Hn];

  const int tid = threadIdx.x;
  const int oo  = tid & 127;              // L1/L2 output row
  const int q   = tid >> 7;               // k-split group 0..3
  const int b0  = blockIdx.x * BT;

  // ---- weights -> registers (112 f32/thread) ----
  f4v w3r[16];                            // vw3 row tid, k in [0,64)
  {
    const f4v* p3 = (const f4v*)(vw3 + tid * Wn);
    #pragma unroll
    for (int i = 0; i < 16; ++i) w3r[i] = p3[i];
    // other k-half -> LDS, [k4][row] layout (lane-consecutive)
    #pragma unroll
    for (int k4 = 0; k4 < 16; ++k4) w3L[k4][tid] = p3[16 + k4];
  }
  f4v w2r[8];                             // vw2 row oo, k in [q*32, q*32+32)
  {
    const f4v* p2 = (const f4v*)(vw2 + oo * Wn + q * 32);
    #pragma unroll
    for (int i = 0; i < 8; ++i) w2r[i] = p2[i];
  }
  f4v w1r[4];                             // vw1 row oo, k in [q*16, q*16+16)
  {
    const f4v* p1 = (const f4v*)(vw1 + oo * Hn + q * 16);
    #pragma unroll
    for (int i = 0; i < 4; ++i) w1r[i] = p1[i];
  }
  const float b3r = vb3[tid];
  const float b2r = vb2[oo];
  const float b1r = vb1[oo];
  const float lb0 = lb[0];

  if (tid < Hn) lw_l[tid] = lw[tid];
  __syncthreads();

  // ---- initial MLP (relu, relu, identity), f32, reads xs from global ----
  {
    float acc = ib1[oo];
    const float* xrow = xs + (b0 + q) * (Tn * Dn);   // X(t0) = xs[:,0]
    #pragma unroll
    for (int k = 0; k < Dn; ++k) acc += iw1[oo * Dn + k] * xrow[k];
    h1_l[q][oo] = fmaxf(acc, 0.f);
  }
  __syncthreads();
  {
    float acc = ib2[oo];
    const f4v* wrow = (const f4v*)(iw2 + oo * Wn);
    #pragma unroll
    for (int k4 = 0; k4 < Wn / 4; ++k4)
      acc += dot4v(wrow[k4], *(const f4v*)&h1_l[q][k4 * 4]);
    h2_l[q][oo] = fmaxf(acc, 0.f);
  }
  __syncthreads();
  if (tid < BT * Hn) {
    const int b = tid >> 6, h = tid & (Hn - 1);
    float acc = ib3[h];
    const f4v* wrow = (const f4v*)(iw3 + h * Wn);
    #pragma unroll
    for (int k4 = 0; k4 < Wn / 4; ++k4)
      acc += dot4v(wrow[k4], *(const f4v*)&h2_l[b][k4 * 4]);
    y_l[b][h] = acc;
  }
  __syncthreads();

  auto readout = [&](int t) {
    if (tid < BT * Hn) {
      const int wv = tid >> 6, h = tid & (Hn - 1);
      float p = lw_l[h] * y_l[wv][h];
      #pragma unroll
      for (int off = 32; off > 0; off >>= 1) p += __shfl_xor(p, off, 64);
      if (h == 0) out[(b0 + wv) * Tn + t] = 1.f / (1.f + expf(-(p + lb0)));
    }
  };
  readout(0);

  // ---- 63 Tsit5 steps ----
  for (int t = 0; t < Tn - 1; ++t) {
    if (tid < BT * Hn) {
      const int b = tid >> 6, h = tid & (Hn - 1);
      ys_l[b][h] = y_l[b][h];
    } else if (tid < BT * Hn + BT * Dn) {
      const int r = tid - BT * Hn;
      const int b = r >> 3, d = r & 7;
      const float* xr = xs + (b0 + b) * (Tn * Dn) + t * Dn + d;
      dxs_l[b][d] = xr[Dn] - xr[0];       // == dt * dX/dt (K absorbs dt)
    }
    __syncthreads();

    #pragma unroll 1
    for (int s = 0; s < 6; ++s) {
      // ---- vf L1: [4,64]->[4,128] f32, k-split 4 ways ----
      {
        float a0 = 0, a1 = 0, a2 = 0, a3 = 0;
        #pragma unroll
        for (int c = 0; c < 4; ++c) {
          const f4v w = w1r[c];
          a0 += dot4v(w, *(const f4v*)&ys_l[0][q * 16 + c * 4]);
          a1 += dot4v(w, *(const f4v*)&ys_l[1][q * 16 + c * 4]);
          a2 += dot4v(w, *(const f4v*)&ys_l[2][q * 16 + c * 4]);
          a3 += dot4v(w, *(const f4v*)&ys_l[3][q * 16 + c * 4]);
        }
        part_l[q][0][oo] = a0; part_l[q][1][oo] = a1;
        part_l[q][2][oo] = a2; part_l[q][3][oo] = a3;
      }
      __syncthreads();
      {
        float acc = b1r;
        #pragma unroll
        for (int j = 0; j < 4; ++j) acc += part_l[j][q][oo];
        h1_l[q][oo] = softplus_f(acc);
      }
      __syncthreads();
      // ---- vf L2: [4,128]->[4,128] f32, k-split 4 ways ----
      {
        float a0 = 0, a1 = 0, a2 = 0, a3 = 0;
        #pragma unroll
        for (int c = 0; c < 8; ++c) {
          const f4v w = w2r[c];
          a0 += dot4v(w, *(const f4v*)&h1_l[0][q * 32 + c * 4]);
          a1 += dot4v(w, *(const f4v*)&h1_l[1][q * 32 + c * 4]);
          a2 += dot4v(w, *(const f4v*)&h1_l[2][q * 32 + c * 4]);
          a3 += dot4v(w, *(const f4v*)&h1_l[3][q * 32 + c * 4]);
        }
        part_l[q][0][oo] = a0; part_l[q][1][oo] = a1;
        part_l[q][2][oo] = a2; part_l[q][3][oo] = a3;
      }
      __syncthreads();
      {
        float acc = b2r;
        #pragma unroll
        for (int j = 0; j < 4; ++j) acc += part_l[j][q][oo];
        h2_l[q][oo] = softplus_f(acc);
      }
      __syncthreads();
      // ---- vf L3: [4,128]->[4,512], f32; k-half from regs, k-half LDS ----
      {
        float a0 = 0, a1 = 0, a2 = 0, a3 = 0;
        #pragma unroll
        for (int c = 0; c < 16; ++c) {      // k in [0,64): register weights
          const f4v w = w3r[c];
          a0 += dot4v(w, *(const f4v*)&h2_l[0][c * 4]);
          a1 += dot4v(w, *(const f4v*)&h2_l[1][c * 4]);
          a2 += dot4v(w, *(const f4v*)&h2_l[2][c * 4]);
          a3 += dot4v(w, *(const f4v*)&h2_l[3][c * 4]);
        }
        #pragma unroll
        for (int k4 = 0; k4 < 16; ++k4) {   // k in [64,128): LDS weights
          const f4v w = w3L[k4][tid];
          a0 += dot4v(w, *(const f4v*)&h2_l[0][64 + k4 * 4]);
          a1 += dot4v(w, *(const f4v*)&h2_l[1][64 + k4 * 4]);
          a2 += dot4v(w, *(const f4v*)&h2_l[2][64 + k4 * 4]);
          a3 += dot4v(w, *(const f4v*)&h2_l[3][64 + k4 * 4]);
        }
        const int d = tid & 7, h = tid >> 3;   // row tid = h*8+d
        #define L3RED(ab, b) {                                 \
          float p = tanhf(ab + b3r) * dxs_l[b][d];             \
          p += __shfl_xor(p, 1, 64);                           \
          p += __shfl_xor(p, 2, 64);                           \
          p += __shfl_xor(p, 4, 64);                           \
          if (d == 0) K_l[s][b][h] = p; }
        L3RED(a0, 0) L3RED(a1, 1) L3RED(a2, 2) L3RED(a3, 3)
        #undef L3RED
      }
      __syncthreads();
      // ---- stage prep / final update ----
      if (tid < BT * Hn) {
        const int b = tid >> 6, h = tid & (Hn - 1);
        float v = y_l[b][h];
        if (s == 0)      v += A21 * K_l[0][b][h];
        else if (s == 1) v += A31 * K_l[0][b][h] + A32 * K_l[1][b][h];
        else if (s == 2) v += A41 * K_l[0][b][h] + A42 * K_l[1][b][h] + A43 * K_l[2][b][h];
        else if (s == 3) v += A51 * K_l[0][b][h] + A52 * K_l[1][b][h] + A53 * K_l[2][b][h] + A54 * K_l[3][b][h];
        else if (s == 4) v += A61 * K_l[0][b][h] + A62 * K_l[1][b][h] + A63 * K_l[2][b][h] + A64 * K_l[3][b][h] + A65 * K_l[4][b][h];
        else             v += Bc1 * K_l[0][b][h] + Bc2 * K_l[1][b][h] + Bc3 * K_l[2][b][h]
                            + Bc4 * K_l[3][b][h] + Bc5 * K_l[4][b][h] + Bc6 * K_l[5][b][h];
        if (s < 5) ys_l[b][h] = v; else y_l[b][h] = v;
      }
      __syncthreads();
    }
    readout(t + 1);
  }
}

extern "C" void kernel_launch(void* const* d_in, const int* in_sizes, int n_in,
                              void* d_out, int out_size, void* d_ws, size_t ws_size,
                              hipStream_t stream) {
  const float* xs  = (const float*)d_in[1];
  const float* iw1 = (const float*)d_in[2];
  const float* ib1 = (const float*)d_in[3];
  const float* iw2 = (const float*)d_in[4];
  const float* ib2 = (const float*)d_in[5];
  const float* iw3 = (const float*)d_in[6];
  const float* ib3 = (const float*)d_in[7];
  const float* vw1 = (const float*)d_in[8];
  const float* vb1 = (const float*)d_in[9];
  const float* vw2 = (const float*)d_in[10];
  const float* vb2 = (const float*)d_in[11];
  const float* vw3 = (const float*)d_in[12];
  const float* vb3 = (const float*)d_in[13];
  const float* lw  = (const float*)d_in[14];
  const float* lb  = (const float*)d_in[15];
  float* out = (float*)d_out;

  ncde_kernel<<<Bb / BT, NT, 0, stream>>>(xs, iw1, ib1, iw2, ib2, iw3, ib3,
                                          vw1, vb1, vw2, vb2, vw3, vb3, lw, lb, out);
}